// Round 15
// baseline (158.139 us; speedup 1.0000x reference)
//
#include <hip/hip_runtime.h>
#include <hip/hip_bf16.h>

// SNNonLocalBlock: B=16, H=W=64, C=256, L=4096, Ld=1024
// Round 15: round-10's 512-thread 8-wave k_attn (proven correct; was spilled
// by __launch_bounds__(512,8) -> VGPR cap 32) re-run with (512,6): cap 85,
// 24 waves/CU (3 blocks x 8 waves), no spill. + r14-proven cvt_pk packing.
// k_prep / k_proj identical to round 14.

typedef __attribute__((ext_vector_type(8))) short bf16x8;
typedef __attribute__((ext_vector_type(4))) float f32x4;

#define MFMA16(A,B,C) __builtin_amdgcn_mfma_f32_16x16x32_bf16(A,B,C,0,0,0)

#define GLOAD16(GSRC, LDST)                                                        \
    __builtin_amdgcn_global_load_lds(                                              \
        (const __attribute__((address_space(1))) unsigned int*)(GSRC),             \
        (__attribute__((address_space(3))) unsigned int*)(LDST), 16, 0, 0)

static __device__ __forceinline__ unsigned short f2b(float f) {
    __hip_bfloat16 h = __float2bfloat16(f);
    return *reinterpret_cast<unsigned short*>(&h);
}
static __device__ __forceinline__ unsigned short bmax(unsigned short a, unsigned short b) {
    return (__uint_as_float((unsigned)a << 16) > __uint_as_float((unsigned)b << 16)) ? a : b;
}
static __device__ __forceinline__ float fexp2(float f) {
    return __builtin_amdgcn_exp2f(f);
}
static __device__ __forceinline__ unsigned cvt_pk_bf16(float lo, float hi) {
    unsigned r;
    asm("v_cvt_pk_bf16_f32 %0, %1, %2" : "=v"(r) : "v"(lo), "v"(hi));
    return r;
}

// ---------------------------------------------------------------------------
// K0: prep: WT[192 n][256 k] bf16 = [w_theta*log2e | w_phi | w_g]^T ;
//           woT[256 c][128 d] bf16
// ---------------------------------------------------------------------------
__global__ void k_prep(const float* __restrict__ w_theta, const float* __restrict__ w_phi,
                       const float* __restrict__ w_g, const float* __restrict__ w_o,
                       unsigned short* __restrict__ WT, unsigned short* __restrict__ woT)
{
    int bid = blockIdx.x, t = threadIdx.x;
    if (bid < 192) {
        int n = bid;
        float v;
        if (n < 32)      v = w_theta[t * 32 + n] * 1.44269504f;  // fold log2e -> exp2
        else if (n < 64) v = w_phi[t * 32 + (n - 32)];
        else             v = w_g[t * 128 + (n - 64)];
        WT[n * 256 + t] = f2b(v);
    } else if (t < 128) {
        int cc = bid - 192;
        woT[cc * 128 + t] = f2b(w_o[t * 256 + cc]);
    }
}

// ---------------------------------------------------------------------------
// K1: fused proj + pool (identical to round 14).
// ---------------------------------------------------------------------------
__global__ __launch_bounds__(256) void k_proj(
    const float* __restrict__ x, const unsigned short* __restrict__ WT,
    unsigned short* __restrict__ theta_b, unsigned short* __restrict__ phi_p,
    unsigned short* __restrict__ g_pT)
{
    __shared__ char plds[40960];
    unsigned short* xT = (unsigned short*)plds;            // [128][64k] swz, 16KB
    unsigned short* wT = (unsigned short*)(plds + 16384);  // [192][64k] swz, 24KB

    const int t = threadIdx.x;
    const int w = t >> 6, l = t & 63, G = l >> 4, c = l & 15;
    const int bid = blockIdx.x;
    const int b = bid >> 5, h2 = bid & 31;
    const size_t row0 = (size_t)bid * 128;

    f32x4 acc[2][12];
#pragma unroll
    for (int i = 0; i < 2; i++)
#pragma unroll
        for (int j = 0; j < 12; j++) acc[i][j] = (f32x4){0.f, 0.f, 0.f, 0.f};

    for (int k0 = 0; k0 < 256; k0 += 64) {
        __syncthreads();
#pragma unroll
        for (int it = 0; it < 4; it++) {           // x tile: 128 rows x 8 slots
            int u = it * 256 + t, r = u >> 3, s = u & 7;
            const float* px = x + (row0 + r) * 256 + k0 + s * 8;
            float4 a = *(const float4*)px;
            float4 bq = *(const float4*)(px + 4);
            uint4 v;
            v.x = (unsigned)f2b(a.x) | ((unsigned)f2b(a.y) << 16);
            v.y = (unsigned)f2b(a.z) | ((unsigned)f2b(a.w) << 16);
            v.z = (unsigned)f2b(bq.x) | ((unsigned)f2b(bq.y) << 16);
            v.w = (unsigned)f2b(bq.z) | ((unsigned)f2b(bq.w) << 16);
            *(uint4*)((char*)xT + r * 128 + ((s * 16) ^ ((r & 7) << 4))) = v;
        }
#pragma unroll
        for (int it = 0; it < 6; it++) {           // W tile: 192 rows x 8 slots
            int u = it * 256 + t, r = u >> 3, s = u & 7;
            uint4 v = *(const uint4*)(WT + r * 256 + k0 + s * 8);
            *(uint4*)((char*)wT + r * 128 + ((s * 16) ^ ((r & 7) << 4))) = v;
        }
        __syncthreads();
#pragma unroll
        for (int kin = 0; kin < 2; kin++) {
            int m0r = (2 * w) * 16 + c, m1r = (2 * w + 1) * 16 + c;
            bf16x8 a0 = *(const bf16x8*)((char*)xT + m0r * 128 + ((kin * 64 + G * 16) ^ ((m0r & 7) << 4)));
            bf16x8 a1 = *(const bf16x8*)((char*)xT + m1r * 128 + ((kin * 64 + G * 16) ^ ((m1r & 7) << 4)));
#pragma unroll
            for (int nt = 0; nt < 12; nt++) {
                int nr = nt * 16 + c;
                bf16x8 bv = *(const bf16x8*)((char*)wT + nr * 128 + ((kin * 64 + G * 16) ^ ((nr & 7) << 4)));
                acc[0][nt] = MFMA16(a0, bv, acc[0][nt]);
                acc[1][nt] = MFMA16(a1, bv, acc[1][nt]);
            }
        }
    }

    // theta -> global (full-res), nt 0..1
#pragma unroll
    for (int mt = 0; mt < 2; mt++)
#pragma unroll
        for (int nt = 0; nt < 2; nt++)
#pragma unroll
            for (int i = 0; i < 4; i++) {
                size_t row = row0 + (2 * w + mt) * 16 + 4 * G + i;
                theta_b[row * 32 + nt * 16 + c] = f2b(acc[mt][nt][i]);
            }

    __syncthreads();   // all MFMA reads of xT/wT done before overwrite

    // ww-pooled tile T[64 rows][160 cols]: row = rr*32 + wp, 512B stride
#pragma unroll
    for (int mt = 0; mt < 2; mt++) {
        int rl = 2 * w + mt, rr = rl >> 2, wpb = (rl & 3) * 8 + 2 * G;
#pragma unroll
        for (int nt = 2; nt < 12; nt++) {
            int col = (nt - 2) * 16 + c;
#pragma unroll
            for (int j = 0; j < 2; j++) {
                int row = rr * 32 + wpb + j;
                float m = fmaxf(acc[mt][nt][2 * j], acc[mt][nt][2 * j + 1]);
                *(unsigned short*)(plds + row * 512 + ((2 * col) ^ ((row & 7) << 4))) = f2b(m);
            }
        }
    }
    __syncthreads();

    // phi: rr-pool cols 0..31 -> phi_p[b][h2*32+wp][ch]
    {
        int wp = t >> 3, chb = (t & 7) * 4;
        unsigned short vv[4];
#pragma unroll
        for (int k = 0; k < 4; k++) {
            int colb = 2 * (chb + k);
            unsigned short a = *(const unsigned short*)(plds + wp * 512 + (colb ^ ((wp & 7) << 4)));
            unsigned short e = *(const unsigned short*)(plds + (wp + 32) * 512 + (colb ^ ((wp & 7) << 4)));
            vv[k] = bmax(a, e);
        }
        uint2 pv;
        pv.x = (unsigned)vv[0] | ((unsigned)vv[1] << 16);
        pv.y = (unsigned)vv[2] | ((unsigned)vv[3] << 16);
        *(uint2*)(phi_p + ((size_t)(b * 1024 + h2 * 32 + wp)) * 32 + chb) = pv;
    }
    // g: rr-pool cols 32..159, transpose + k-perm -> g_pT[b][d][h2*32 + s4*8 + k]
#pragma unroll
    for (int it = 0; it < 2; it++) {
        int d = t & 127, s4 = (t >> 7) + 2 * it;
        union { unsigned short v[8]; uint4 q; } pk;
#pragma unroll
        for (int k = 0; k < 8; k++) {
            int wp2 = 16 * (k >> 2) + 4 * s4 + (k & 3);
            int colb = 2 * (32 + d);
            unsigned short a = *(const unsigned short*)(plds + wp2 * 512 + (colb ^ ((wp2 & 7) << 4)));
            unsigned short e = *(const unsigned short*)(plds + (wp2 + 32) * 512 + (colb ^ ((wp2 & 7) << 4)));
            pk.v[k] = bmax(a, e);
        }
        *(uint4*)(g_pT + ((size_t)b * 128 + d) * 1024 + h2 * 32 + s4 * 8) = pk.q;
    }
}

// ---------------------------------------------------------------------------
// K3: fused flash attention. 1024 blocks x 512 thr. 8 waves = 4 qg x 2 mg.
// Wave (qg,mg): 16q x 512m as 16 chunks of 32m. 1 barrier/chunk.
// __launch_bounds__(512,6): VGPR cap 85 (no spill), 24 waves/CU.
// ---------------------------------------------------------------------------
__global__ __launch_bounds__(512, 6) void k_attn(
    const unsigned short* __restrict__ theta_b, const unsigned short* __restrict__ phi_p,
    const unsigned short* __restrict__ g_pT, const unsigned short* __restrict__ woT,
    const float* __restrict__ x, const float* __restrict__ b_o,
    const float* __restrict__ sigma_p, float* __restrict__ out)
{
    // main: buf(mg,bi) @ mg*20480 + bi*10240: g 8KB [128d][64B] | phi 2KB @+8192
    // theta prologue @10240 [64 x 64B]. Combine: po qg @ qg*8320 (16r x 520B),
    // ps @33280 (256B). Epilogue: O_l @0 (16KB [64q][256B] swz), wo_l halves
    // @16384 + h*8192 (8KB each). Total 40960.
    __shared__ char lds[40960];

    const int t = threadIdx.x;
    const int w = t >> 6, l = t & 63, G = l >> 4, c = l & 15;
    const int qg = w >> 1, mg = w & 1;
    const int bid = (blockIdx.x & 7) * 128 + (blockIdx.x >> 3);   // XCD swizzle (bijective)
    const int b = bid >> 6;
    const int q0 = (bid & 63) * 64;
    const int xr = (c & 7) << 4;

    const unsigned short* gsrc = g_pT + (size_t)b * 131072;
    const unsigned short* psrc = phi_p + (size_t)b * 32768;
    // per mg per chunk: 8 g-loads + 2 phi-loads, split over 4 qg waves
#define STAGE(BI, MC)                                                               \
    {                                                                               \
        char* gb = lds + mg * 20480 + (BI) * 10240;                                 \
        char* pb = gb + 8192;                                                       \
        const int hp = mg * 16 + (MC);                                              \
        _Pragma("unroll")                                                           \
        for (int it = 0; it < 2; it++) {                                            \
            int d = qg * 32 + it * 16 + (l >> 2);                                   \
            GLOAD16(gsrc + (size_t)d * 1024 + hp * 32 + (l & 3) * 8,                \
                    gb + qg * 2048 + it * 1024 + l * 16);                           \
        }                                                                           \
        if (qg < 2) {                                                               \
            int r = qg * 16 + (l >> 2);                                             \
            GLOAD16(psrc + (size_t)(hp * 32 + r) * 32 + (l & 3) * 8,                \
                    pb + qg * 1024 + l * 16);                                       \
        }                                                                           \
    }

    // prologue: stage chunk 0 (both mg) + theta [64q][32ch] plain @10240
    STAGE(0, 0);
    {
        char* th = lds + 10240;
        int r = t >> 3, s = t & 7;
        uint2 v = *(const uint2*)(theta_b + ((size_t)(b * 4096 + q0 + r)) * 32 + s * 4);
        *(uint2*)(th + r * 64 + s * 8) = v;
    }
    __syncthreads();   // chunk0 + theta landed (drains vmcnt+lgkm)

    // wave's theta B-frag: q rows [qg*16, qg*16+16)
    const bf16x8 bt = *(const bf16x8*)(lds + 10240 + (qg * 16 + c) * 64 + G * 16);
    __syncthreads();   // bt reads done before iter0 stages buf(0,1) (theta region)

    f32x4 oacc[8];
#pragma unroll
    for (int dt = 0; dt < 8; dt++) oacc[dt] = (f32x4){0.f, 0.f, 0.f, 0.f};
    float ps = 0.f;
    const f32x4 zf = (f32x4){0.f, 0.f, 0.f, 0.f};

    for (int mc = 0; mc < 16; mc++) {
        const int cur = mc & 1;
        asm volatile("s_waitcnt vmcnt(0)" ::: "memory");
        __builtin_amdgcn_sched_barrier(0);
        __builtin_amdgcn_s_barrier();
        __builtin_amdgcn_sched_barrier(0);
        if (mc < 15) STAGE(cur ^ 1, mc + 1);    // lands under compute(mc)

        const char* gL   = lds + mg * 20480 + cur * 10240;
        const char* phiL = gL + 8192;

        // S^T = phi @ theta^T (K=32 ch, 2 m-tiles x 1 q-tile)
        bf16x8 ap0 = *(const bf16x8*)(phiL + c * 64 + G * 16);
        bf16x8 ap1 = *(const bf16x8*)(phiL + (16 + c) * 64 + G * 16);
        f32x4 sacc[2];
        __builtin_amdgcn_s_setprio(1);
        sacc[0] = MFMA16(ap0, bt, zf);
        sacc[1] = MFMA16(ap1, bt, zf);
        __builtin_amdgcn_s_setprio(0);

        // exp2 -> packed P A-frag (slot j: m = 16*(j>>2) + 4G + (j&3)) + rowsum
        bf16x8 pa;
        {
            union { unsigned u[4]; bf16x8 v; } pu;
#pragma unroll
            for (int mt = 0; mt < 2; mt++)
#pragma unroll
                for (int hf = 0; hf < 2; hf++) {
                    float p0 = fexp2(sacc[mt][2 * hf]);
                    float p1 = fexp2(sacc[mt][2 * hf + 1]);
                    ps += p0 + p1;
                    pu.u[mt * 2 + hf] = cvt_pk_bf16(p0, p1);
                }
            pa = pu.v;
        }

        // O += P @ g  (B-frag = one dense b128 per d-tile)
        __builtin_amdgcn_s_setprio(1);
#pragma unroll
        for (int dt = 0; dt < 8; dt++) {
            bf16x8 bg = *(const bf16x8*)(gL + (dt * 16 + c) * 64 + G * 16);
            oacc[dt] = MFMA16(pa, bg, oacc[dt]);
        }
        __builtin_amdgcn_s_setprio(0);
    }
#undef STAGE
    __syncthreads();   // all compute(15) reads done before combine overwrites lds

    // wave rowsum: lanes {c,c+16,c+32,c+48} hold partials for q = qg*16 + c
    ps += __shfl_xor(ps, 16);
    ps += __shfl_xor(ps, 32);

    // ---- combine m-group partials ----
    if (mg == 1) {
        char* po = lds + qg * 8320;
#pragma unroll
        for (int dt = 0; dt < 8; dt++)
#pragma unroll
            for (int i = 0; i < 4; i++)
                *(float*)(po + (4 * G + i) * 520 + (dt * 16 + c) * 4) = oacc[dt][i];
        if (l < 16)
            *(float*)(lds + 33280 + (qg * 16 + l) * 4) = ps;
    }
    __syncthreads();
    float rinv[4];
    if (mg == 0) {
        const char* po = lds + qg * 8320;
#pragma unroll
        for (int dt = 0; dt < 8; dt++) {
            f32x4 a = oacc[dt];
#pragma unroll
            for (int i = 0; i < 4; i++)
                a[i] += *(const float*)(po + (4 * G + i) * 520 + (dt * 16 + c) * 4);
            oacc[dt] = a;
        }
        ps += *(const float*)(lds + 33280 + (qg * 16 + c) * 4);
#pragma unroll
        for (int i = 0; i < 4; i++) rinv[i] = 1.0f / __shfl(ps, 4 * G + i);
    }
    __syncthreads();   // all po/ps reads done before O_l overwrites
    if (mg == 0) {
        // normalized O -> O_l [64 q][128 d] bf16 @0
#pragma unroll
        for (int dt = 0; dt < 8; dt++)
#pragma unroll
            for (int i = 0; i < 4; i++) {
                int row = qg * 16 + 4 * G + i, d = dt * 16 + c;
                *(unsigned short*)(lds + row * 256 + ((d * 2) ^ ((row & 7) << 4))) =
                    f2b(oacc[dt][i] * rinv[i]);
            }
    }
    __syncthreads();   // O_l visible to all

    // ---- epilogue: out = x + sigma * (O @ w_o + b_o) ----
    // wave w: q rows (w&3)*16..+16, col half h = w>>2 (128 cols as 4 cb of 32)
    const float sg = *sigma_p;
    const int wq = w & 3, h = w >> 2;
    const char* O_r = lds + (wq * 16 + c) * 256;
    char* wo_h = lds + 16384 + h * 8192;
    bf16x8 aO[4];
#pragma unroll
    for (int ks = 0; ks < 4; ks++)
        aO[ks] = *(const bf16x8*)(O_r + ((ks * 64 + G * 16) ^ xr));

    const int th256 = wq * 64 + l;     // 0..255 within col-half group
    for (int cb = 0; cb < 4; cb++) {
        __syncthreads();                         // prev wo reads done
#pragma unroll
        for (int it = 0; it < 2; it++) {         // stage woT slice [32 c][128 d] = 8KB
            int u = it * 256 + th256, r = u >> 4, s = u & 15;
            uint4 v = *(const uint4*)(woT + (size_t)(h * 128 + cb * 32 + r) * 128 + s * 8);
            *(uint4*)(wo_h + r * 256 + ((s * 16) ^ ((r & 7) << 4))) = v;
        }
        __syncthreads();
        f32x4 eacc[2];
#pragma unroll
        for (int ct = 0; ct < 2; ct++) eacc[ct] = (f32x4){0.f, 0.f, 0.f, 0.f};
#pragma unroll
        for (int ks = 0; ks < 4; ks++) {
#pragma unroll
            for (int ct = 0; ct < 2; ct++) {
                bf16x8 bw = *(const bf16x8*)(wo_h + (ct * 16 + c) * 256 + ((ks * 64 + G * 16) ^ xr));
                eacc[ct] = MFMA16(aO[ks], bw, eacc[ct]);
            }
        }
#pragma unroll
        for (int ct = 0; ct < 2; ct++) {
            int col = h * 128 + cb * 32 + ct * 16 + c;
            float bo = b_o[col];
#pragma unroll
            for (int i = 0; i < 4; i++) {
                size_t off = ((size_t)(b * 4096 + q0 + wq * 16 + 4 * G + i)) * 256 + col;
                out[off] = x[off] + sg * (eacc[ct][i] + bo);
            }
        }
    }
}

// ---------------------------------------------------------------------------
extern "C" void kernel_launch(void* const* d_in, const int* in_sizes, int n_in,
                              void* d_out, int out_size, void* d_ws, size_t ws_size,
                              hipStream_t stream)
{
    const float* x       = (const float*)d_in[0];
    const float* w_theta = (const float*)d_in[1];
    const float* w_phi   = (const float*)d_in[2];
    const float* w_g     = (const float*)d_in[3];
    const float* w_o     = (const float*)d_in[4];
    const float* b_o     = (const float*)d_in[5];
    const float* sigma   = (const float*)d_in[6];
    float* out = (float*)d_out;

    char* ws = (char*)d_ws;
    unsigned short* theta_b = (unsigned short*)(ws);              //  4 MB [B,4096,32]
    unsigned short* phi_p   = (unsigned short*)(ws + 4194304);    //  1 MB [B,1024,32]
    unsigned short* g_pT    = (unsigned short*)(ws + 5242880);    //  4 MB [B,128,1024] k-perm
    unsigned short* WT      = (unsigned short*)(ws + 9437184);    // 96 KB [192,256]
    unsigned short* woT     = (unsigned short*)(ws + 9535488);    // 64 KB [256,128]

    hipLaunchKernelGGL(k_prep, dim3(448), dim3(256), 0, stream,
                       w_theta, w_phi, w_g, w_o, WT, woT);
    hipLaunchKernelGGL(k_proj, dim3(512), dim3(256), 0, stream,
                       x, WT, theta_b, phi_p, g_pT);
    hipLaunchKernelGGL(k_attn, dim3(1024), dim3(512), 0, stream,
                       theta_b, phi_p, g_pT, woT, x, b_o, sigma, out);
}

// Round 16
// 95.706 us; speedup vs baseline: 1.6523x; 1.6523x over previous
//
#include <hip/hip_runtime.h>
#include <hip/hip_bf16.h>

// SNNonLocalBlock: B=16, H=W=64, C=256, L=4096, Ld=1024
// Round 16 = Round 15 with __launch_bounds__(512) (NO min-waves arg).
// (512,8)->VGPR cap 32 and (512,6)->40 both made hipcc spill a structure
// that needs ~64 VGPRs; unhinted it should allocate ~64 -> 8 waves/SIMD
// possible, LDS 40KB -> 4 blocks x 8 waves = up to 32 waves/CU.

typedef __attribute__((ext_vector_type(8))) short bf16x8;
typedef __attribute__((ext_vector_type(4))) float f32x4;

#define MFMA16(A,B,C) __builtin_amdgcn_mfma_f32_16x16x32_bf16(A,B,C,0,0,0)

#define GLOAD16(GSRC, LDST)                                                        \
    __builtin_amdgcn_global_load_lds(                                              \
        (const __attribute__((address_space(1))) unsigned int*)(GSRC),             \
        (__attribute__((address_space(3))) unsigned int*)(LDST), 16, 0, 0)

static __device__ __forceinline__ unsigned short f2b(float f) {
    __hip_bfloat16 h = __float2bfloat16(f);
    return *reinterpret_cast<unsigned short*>(&h);
}
static __device__ __forceinline__ unsigned short bmax(unsigned short a, unsigned short b) {
    return (__uint_as_float((unsigned)a << 16) > __uint_as_float((unsigned)b << 16)) ? a : b;
}
static __device__ __forceinline__ float fexp2(float f) {
    return __builtin_amdgcn_exp2f(f);
}
static __device__ __forceinline__ unsigned cvt_pk_bf16(float lo, float hi) {
    unsigned r;
    asm("v_cvt_pk_bf16_f32 %0, %1, %2" : "=v"(r) : "v"(lo), "v"(hi));
    return r;
}

// ---------------------------------------------------------------------------
// K0: prep: WT[192 n][256 k] bf16 = [w_theta*log2e | w_phi | w_g]^T ;
//           woT[256 c][128 d] bf16
// ---------------------------------------------------------------------------
__global__ void k_prep(const float* __restrict__ w_theta, const float* __restrict__ w_phi,
                       const float* __restrict__ w_g, const float* __restrict__ w_o,
                       unsigned short* __restrict__ WT, unsigned short* __restrict__ woT)
{
    int bid = blockIdx.x, t = threadIdx.x;
    if (bid < 192) {
        int n = bid;
        float v;
        if (n < 32)      v = w_theta[t * 32 + n] * 1.44269504f;  // fold log2e -> exp2
        else if (n < 64) v = w_phi[t * 32 + (n - 32)];
        else             v = w_g[t * 128 + (n - 64)];
        WT[n * 256 + t] = f2b(v);
    } else if (t < 128) {
        int cc = bid - 192;
        woT[cc * 128 + t] = f2b(w_o[t * 256 + cc]);
    }
}

// ---------------------------------------------------------------------------
// K1: fused proj + pool (identical to round 14).
// ---------------------------------------------------------------------------
__global__ __launch_bounds__(256) void k_proj(
    const float* __restrict__ x, const unsigned short* __restrict__ WT,
    unsigned short* __restrict__ theta_b, unsigned short* __restrict__ phi_p,
    unsigned short* __restrict__ g_pT)
{
    __shared__ char plds[40960];
    unsigned short* xT = (unsigned short*)plds;            // [128][64k] swz, 16KB
    unsigned short* wT = (unsigned short*)(plds + 16384);  // [192][64k] swz, 24KB

    const int t = threadIdx.x;
    const int w = t >> 6, l = t & 63, G = l >> 4, c = l & 15;
    const int bid = blockIdx.x;
    const int b = bid >> 5, h2 = bid & 31;
    const size_t row0 = (size_t)bid * 128;

    f32x4 acc[2][12];
#pragma unroll
    for (int i = 0; i < 2; i++)
#pragma unroll
        for (int j = 0; j < 12; j++) acc[i][j] = (f32x4){0.f, 0.f, 0.f, 0.f};

    for (int k0 = 0; k0 < 256; k0 += 64) {
        __syncthreads();
#pragma unroll
        for (int it = 0; it < 4; it++) {           // x tile: 128 rows x 8 slots
            int u = it * 256 + t, r = u >> 3, s = u & 7;
            const float* px = x + (row0 + r) * 256 + k0 + s * 8;
            float4 a = *(const float4*)px;
            float4 bq = *(const float4*)(px + 4);
            uint4 v;
            v.x = (unsigned)f2b(a.x) | ((unsigned)f2b(a.y) << 16);
            v.y = (unsigned)f2b(a.z) | ((unsigned)f2b(a.w) << 16);
            v.z = (unsigned)f2b(bq.x) | ((unsigned)f2b(bq.y) << 16);
            v.w = (unsigned)f2b(bq.z) | ((unsigned)f2b(bq.w) << 16);
            *(uint4*)((char*)xT + r * 128 + ((s * 16) ^ ((r & 7) << 4))) = v;
        }
#pragma unroll
        for (int it = 0; it < 6; it++) {           // W tile: 192 rows x 8 slots
            int u = it * 256 + t, r = u >> 3, s = u & 7;
            uint4 v = *(const uint4*)(WT + r * 256 + k0 + s * 8);
            *(uint4*)((char*)wT + r * 128 + ((s * 16) ^ ((r & 7) << 4))) = v;
        }
        __syncthreads();
#pragma unroll
        for (int kin = 0; kin < 2; kin++) {
            int m0r = (2 * w) * 16 + c, m1r = (2 * w + 1) * 16 + c;
            bf16x8 a0 = *(const bf16x8*)((char*)xT + m0r * 128 + ((kin * 64 + G * 16) ^ ((m0r & 7) << 4)));
            bf16x8 a1 = *(const bf16x8*)((char*)xT + m1r * 128 + ((kin * 64 + G * 16) ^ ((m1r & 7) << 4)));
#pragma unroll
            for (int nt = 0; nt < 12; nt++) {
                int nr = nt * 16 + c;
                bf16x8 bv = *(const bf16x8*)((char*)wT + nr * 128 + ((kin * 64 + G * 16) ^ ((nr & 7) << 4)));
                acc[0][nt] = MFMA16(a0, bv, acc[0][nt]);
                acc[1][nt] = MFMA16(a1, bv, acc[1][nt]);
            }
        }
    }

    // theta -> global (full-res), nt 0..1
#pragma unroll
    for (int mt = 0; mt < 2; mt++)
#pragma unroll
        for (int nt = 0; nt < 2; nt++)
#pragma unroll
            for (int i = 0; i < 4; i++) {
                size_t row = row0 + (2 * w + mt) * 16 + 4 * G + i;
                theta_b[row * 32 + nt * 16 + c] = f2b(acc[mt][nt][i]);
            }

    __syncthreads();   // all MFMA reads of xT/wT done before overwrite

    // ww-pooled tile T[64 rows][160 cols]: row = rr*32 + wp, 512B stride
#pragma unroll
    for (int mt = 0; mt < 2; mt++) {
        int rl = 2 * w + mt, rr = rl >> 2, wpb = (rl & 3) * 8 + 2 * G;
#pragma unroll
        for (int nt = 2; nt < 12; nt++) {
            int col = (nt - 2) * 16 + c;
#pragma unroll
            for (int j = 0; j < 2; j++) {
                int row = rr * 32 + wpb + j;
                float m = fmaxf(acc[mt][nt][2 * j], acc[mt][nt][2 * j + 1]);
                *(unsigned short*)(plds + row * 512 + ((2 * col) ^ ((row & 7) << 4))) = f2b(m);
            }
        }
    }
    __syncthreads();

    // phi: rr-pool cols 0..31 -> phi_p[b][h2*32+wp][ch]
    {
        int wp = t >> 3, chb = (t & 7) * 4;
        unsigned short vv[4];
#pragma unroll
        for (int k = 0; k < 4; k++) {
            int colb = 2 * (chb + k);
            unsigned short a = *(const unsigned short*)(plds + wp * 512 + (colb ^ ((wp & 7) << 4)));
            unsigned short e = *(const unsigned short*)(plds + (wp + 32) * 512 + (colb ^ ((wp & 7) << 4)));
            vv[k] = bmax(a, e);
        }
        uint2 pv;
        pv.x = (unsigned)vv[0] | ((unsigned)vv[1] << 16);
        pv.y = (unsigned)vv[2] | ((unsigned)vv[3] << 16);
        *(uint2*)(phi_p + ((size_t)(b * 1024 + h2 * 32 + wp)) * 32 + chb) = pv;
    }
    // g: rr-pool cols 32..159, transpose + k-perm -> g_pT[b][d][h2*32 + s4*8 + k]
#pragma unroll
    for (int it = 0; it < 2; it++) {
        int d = t & 127, s4 = (t >> 7) + 2 * it;
        union { unsigned short v[8]; uint4 q; } pk;
#pragma unroll
        for (int k = 0; k < 8; k++) {
            int wp2 = 16 * (k >> 2) + 4 * s4 + (k & 3);
            int colb = 2 * (32 + d);
            unsigned short a = *(const unsigned short*)(plds + wp2 * 512 + (colb ^ ((wp2 & 7) << 4)));
            unsigned short e = *(const unsigned short*)(plds + (wp2 + 32) * 512 + (colb ^ ((wp2 & 7) << 4)));
            pk.v[k] = bmax(a, e);
        }
        *(uint4*)(g_pT + ((size_t)b * 128 + d) * 1024 + h2 * 32 + s4 * 8) = pk.q;
    }
}

// ---------------------------------------------------------------------------
// K3: fused flash attention. 1024 blocks x 512 thr. 8 waves = 4 qg x 2 mg.
// Wave (qg,mg): 16q x 512m as 16 chunks of 32m. 1 barrier/chunk.
// __launch_bounds__(512) with NO min-waves arg: compiler free to use ~64 VGPR.
// ---------------------------------------------------------------------------
__global__ __launch_bounds__(512) void k_attn(
    const unsigned short* __restrict__ theta_b, const unsigned short* __restrict__ phi_p,
    const unsigned short* __restrict__ g_pT, const unsigned short* __restrict__ woT,
    const float* __restrict__ x, const float* __restrict__ b_o,
    const float* __restrict__ sigma_p, float* __restrict__ out)
{
    // main: buf(mg,bi) @ mg*20480 + bi*10240: g 8KB [128d][64B] | phi 2KB @+8192
    // theta prologue @10240 [64 x 64B]. Combine: po qg @ qg*8320 (16r x 520B),
    // ps @33280 (256B). Epilogue: O_l @0 (16KB [64q][256B] swz), wo_l halves
    // @16384 + h*8192 (8KB each). Total 40960.
    __shared__ char lds[40960];

    const int t = threadIdx.x;
    const int w = t >> 6, l = t & 63, G = l >> 4, c = l & 15;
    const int qg = w >> 1, mg = w & 1;
    const int bid = (blockIdx.x & 7) * 128 + (blockIdx.x >> 3);   // XCD swizzle (bijective)
    const int b = bid >> 6;
    const int q0 = (bid & 63) * 64;
    const int xr = (c & 7) << 4;

    const unsigned short* gsrc = g_pT + (size_t)b * 131072;
    const unsigned short* psrc = phi_p + (size_t)b * 32768;
    // per mg per chunk: 8 g-loads + 2 phi-loads, split over 4 qg waves
#define STAGE(BI, MC)                                                               \
    {                                                                               \
        char* gb = lds + mg * 20480 + (BI) * 10240;                                 \
        char* pb = gb + 8192;                                                       \
        const int hp = mg * 16 + (MC);                                              \
        _Pragma("unroll")                                                           \
        for (int it = 0; it < 2; it++) {                                            \
            int d = qg * 32 + it * 16 + (l >> 2);                                   \
            GLOAD16(gsrc + (size_t)d * 1024 + hp * 32 + (l & 3) * 8,                \
                    gb + qg * 2048 + it * 1024 + l * 16);                           \
        }                                                                           \
        if (qg < 2) {                                                               \
            int r = qg * 16 + (l >> 2);                                             \
            GLOAD16(psrc + (size_t)(hp * 32 + r) * 32 + (l & 3) * 8,                \
                    pb + qg * 1024 + l * 16);                                       \
        }                                                                           \
    }

    // prologue: stage chunk 0 (both mg) + theta [64q][32ch] plain @10240
    STAGE(0, 0);
    {
        char* th = lds + 10240;
        int r = t >> 3, s = t & 7;
        uint2 v = *(const uint2*)(theta_b + ((size_t)(b * 4096 + q0 + r)) * 32 + s * 4);
        *(uint2*)(th + r * 64 + s * 8) = v;
    }
    __syncthreads();   // chunk0 + theta landed (drains vmcnt+lgkm)

    // wave's theta B-frag: q rows [qg*16, qg*16+16)
    const bf16x8 bt = *(const bf16x8*)(lds + 10240 + (qg * 16 + c) * 64 + G * 16);
    __syncthreads();   // bt reads done before iter0 stages buf(0,1) (theta region)

    f32x4 oacc[8];
#pragma unroll
    for (int dt = 0; dt < 8; dt++) oacc[dt] = (f32x4){0.f, 0.f, 0.f, 0.f};
    float ps = 0.f;
    const f32x4 zf = (f32x4){0.f, 0.f, 0.f, 0.f};

    for (int mc = 0; mc < 16; mc++) {
        const int cur = mc & 1;
        asm volatile("s_waitcnt vmcnt(0)" ::: "memory");
        __builtin_amdgcn_sched_barrier(0);
        __builtin_amdgcn_s_barrier();
        __builtin_amdgcn_sched_barrier(0);
        if (mc < 15) STAGE(cur ^ 1, mc + 1);    // lands under compute(mc)

        const char* gL   = lds + mg * 20480 + cur * 10240;
        const char* phiL = gL + 8192;

        // S^T = phi @ theta^T (K=32 ch, 2 m-tiles x 1 q-tile)
        bf16x8 ap0 = *(const bf16x8*)(phiL + c * 64 + G * 16);
        bf16x8 ap1 = *(const bf16x8*)(phiL + (16 + c) * 64 + G * 16);
        f32x4 sacc[2];
        __builtin_amdgcn_s_setprio(1);
        sacc[0] = MFMA16(ap0, bt, zf);
        sacc[1] = MFMA16(ap1, bt, zf);
        __builtin_amdgcn_s_setprio(0);

        // exp2 -> packed P A-frag (slot j: m = 16*(j>>2) + 4G + (j&3)) + rowsum
        bf16x8 pa;
        {
            union { unsigned u[4]; bf16x8 v; } pu;
#pragma unroll
            for (int mt = 0; mt < 2; mt++)
#pragma unroll
                for (int hf = 0; hf < 2; hf++) {
                    float p0 = fexp2(sacc[mt][2 * hf]);
                    float p1 = fexp2(sacc[mt][2 * hf + 1]);
                    ps += p0 + p1;
                    pu.u[mt * 2 + hf] = cvt_pk_bf16(p0, p1);
                }
            pa = pu.v;
        }

        // O += P @ g  (B-frag = one dense b128 per d-tile)
        __builtin_amdgcn_s_setprio(1);
#pragma unroll
        for (int dt = 0; dt < 8; dt++) {
            bf16x8 bg = *(const bf16x8*)(gL + (dt * 16 + c) * 64 + G * 16);
            oacc[dt] = MFMA16(pa, bg, oacc[dt]);
        }
        __builtin_amdgcn_s_setprio(0);
    }
#undef STAGE
    __syncthreads();   // all compute(15) reads done before combine overwrites lds

    // wave rowsum: lanes {c,c+16,c+32,c+48} hold partials for q = qg*16 + c
    ps += __shfl_xor(ps, 16);
    ps += __shfl_xor(ps, 32);

    // ---- combine m-group partials ----
    if (mg == 1) {
        char* po = lds + qg * 8320;
#pragma unroll
        for (int dt = 0; dt < 8; dt++)
#pragma unroll
            for (int i = 0; i < 4; i++)
                *(float*)(po + (4 * G + i) * 520 + (dt * 16 + c) * 4) = oacc[dt][i];
        if (l < 16)
            *(float*)(lds + 33280 + (qg * 16 + l) * 4) = ps;
    }
    __syncthreads();
    float rinv[4];
    if (mg == 0) {
        const char* po = lds + qg * 8320;
#pragma unroll
        for (int dt = 0; dt < 8; dt++) {
            f32x4 a = oacc[dt];
#pragma unroll
            for (int i = 0; i < 4; i++)
                a[i] += *(const float*)(po + (4 * G + i) * 520 + (dt * 16 + c) * 4);
            oacc[dt] = a;
        }
        ps += *(const float*)(lds + 33280 + (qg * 16 + c) * 4);
#pragma unroll
        for (int i = 0; i < 4; i++) rinv[i] = 1.0f / __shfl(ps, 4 * G + i);
    }
    __syncthreads();   // all po/ps reads done before O_l overwrites
    if (mg == 0) {
        // normalized O -> O_l [64 q][128 d] bf16 @0
#pragma unroll
        for (int dt = 0; dt < 8; dt++)
#pragma unroll
            for (int i = 0; i < 4; i++) {
                int row = qg * 16 + 4 * G + i, d = dt * 16 + c;
                *(unsigned short*)(lds + row * 256 + ((d * 2) ^ ((row & 7) << 4))) =
                    f2b(oacc[dt][i] * rinv[i]);
            }
    }
    __syncthreads();   // O_l visible to all

    // ---- epilogue: out = x + sigma * (O @ w_o + b_o) ----
    // wave w: q rows (w&3)*16..+16, col half h = w>>2 (128 cols as 4 cb of 32)
    const float sg = *sigma_p;
    const int wq = w & 3, h = w >> 2;
    const char* O_r = lds + (wq * 16 + c) * 256;
    char* wo_h = lds + 16384 + h * 8192;
    bf16x8 aO[4];
#pragma unroll
    for (int ks = 0; ks < 4; ks++)
        aO[ks] = *(const bf16x8*)(O_r + ((ks * 64 + G * 16) ^ xr));

    const int th256 = wq * 64 + l;     // 0..255 within col-half group
    for (int cb = 0; cb < 4; cb++) {
        __syncthreads();                         // prev wo reads done
#pragma unroll
        for (int it = 0; it < 2; it++) {         // stage woT slice [32 c][128 d] = 8KB
            int u = it * 256 + th256, r = u >> 4, s = u & 15;
            uint4 v = *(const uint4*)(woT + (size_t)(h * 128 + cb * 32 + r) * 128 + s * 8);
            *(uint4*)(wo_h + r * 256 + ((s * 16) ^ ((r & 7) << 4))) = v;
        }
        __syncthreads();
        f32x4 eacc[2];
#pragma unroll
        for (int ct = 0; ct < 2; ct++) eacc[ct] = (f32x4){0.f, 0.f, 0.f, 0.f};
#pragma unroll
        for (int ks = 0; ks < 4; ks++) {
#pragma unroll
            for (int ct = 0; ct < 2; ct++) {
                bf16x8 bw = *(const bf16x8*)(wo_h + (ct * 16 + c) * 256 + ((ks * 64 + G * 16) ^ xr));
                eacc[ct] = MFMA16(aO[ks], bw, eacc[ct]);
            }
        }
#pragma unroll
        for (int ct = 0; ct < 2; ct++) {
            int col = h * 128 + cb * 32 + ct * 16 + c;
            float bo = b_o[col];
#pragma unroll
            for (int i = 0; i < 4; i++) {
                size_t off = ((size_t)(b * 4096 + q0 + wq * 16 + 4 * G + i)) * 256 + col;
                out[off] = x[off] + sg * (eacc[ct][i] + bo);
            }
        }
    }
}

// ---------------------------------------------------------------------------
extern "C" void kernel_launch(void* const* d_in, const int* in_sizes, int n_in,
                              void* d_out, int out_size, void* d_ws, size_t ws_size,
                              hipStream_t stream)
{
    const float* x       = (const float*)d_in[0];
    const float* w_theta = (const float*)d_in[1];
    const float* w_phi   = (const float*)d_in[2];
    const float* w_g     = (const float*)d_in[3];
    const float* w_o     = (const float*)d_in[4];
    const float* b_o     = (const float*)d_in[5];
    const float* sigma   = (const float*)d_in[6];
    float* out = (float*)d_out;

    char* ws = (char*)d_ws;
    unsigned short* theta_b = (unsigned short*)(ws);              //  4 MB [B,4096,32]
    unsigned short* phi_p   = (unsigned short*)(ws + 4194304);    //  1 MB [B,1024,32]
    unsigned short* g_pT    = (unsigned short*)(ws + 5242880);    //  4 MB [B,128,1024] k-perm
    unsigned short* WT      = (unsigned short*)(ws + 9437184);    // 96 KB [192,256]
    unsigned short* woT     = (unsigned short*)(ws + 9535488);    // 64 KB [256,128]

    hipLaunchKernelGGL(k_prep, dim3(448), dim3(256), 0, stream,
                       w_theta, w_phi, w_g, w_o, WT, woT);
    hipLaunchKernelGGL(k_proj, dim3(512), dim3(256), 0, stream,
                       x, WT, theta_b, phi_p, g_pT);
    hipLaunchKernelGGL(k_attn, dim3(1024), dim3(512), 0, stream,
                       theta_b, phi_p, g_pT, woT, x, b_o, sigma, out);
}

// Round 17
// 69.720 us; speedup vs baseline: 2.2682x; 1.3727x over previous
//
#include <hip/hip_runtime.h>
#include <hip/hip_bf16.h>

// SNNonLocalBlock: B=16, H=W=64, C=256, L=4096, Ld=1024
// Round 17 = Round 14 (best passing: 68.9us total, k_attn 52.3us) with
// s_setprio removed (m190: null-to-negative in barrier-lockstep loops).
// Structure: 4 waves = 2qg x 2mg, 16 chunks of 32m, 1 barrier/chunk,
// exp2-folded theta, cvt_pk P-packing, fused proj+pool, 40KB LDS.

typedef __attribute__((ext_vector_type(8))) short bf16x8;
typedef __attribute__((ext_vector_type(4))) float f32x4;

#define MFMA16(A,B,C) __builtin_amdgcn_mfma_f32_16x16x32_bf16(A,B,C,0,0,0)

#define GLOAD16(GSRC, LDST)                                                        \
    __builtin_amdgcn_global_load_lds(                                              \
        (const __attribute__((address_space(1))) unsigned int*)(GSRC),             \
        (__attribute__((address_space(3))) unsigned int*)(LDST), 16, 0, 0)

static __device__ __forceinline__ unsigned short f2b(float f) {
    __hip_bfloat16 h = __float2bfloat16(f);
    return *reinterpret_cast<unsigned short*>(&h);
}
static __device__ __forceinline__ unsigned short bmax(unsigned short a, unsigned short b) {
    return (__uint_as_float((unsigned)a << 16) > __uint_as_float((unsigned)b << 16)) ? a : b;
}
static __device__ __forceinline__ float fexp2(float f) {
    return __builtin_amdgcn_exp2f(f);
}
static __device__ __forceinline__ unsigned cvt_pk_bf16(float lo, float hi) {
    unsigned r;
    asm("v_cvt_pk_bf16_f32 %0, %1, %2" : "=v"(r) : "v"(lo), "v"(hi));
    return r;
}

// ---------------------------------------------------------------------------
// K0: prep: WT[192 n][256 k] bf16 = [w_theta*log2e | w_phi | w_g]^T ;
//           woT[256 c][128 d] bf16
// ---------------------------------------------------------------------------
__global__ void k_prep(const float* __restrict__ w_theta, const float* __restrict__ w_phi,
                       const float* __restrict__ w_g, const float* __restrict__ w_o,
                       unsigned short* __restrict__ WT, unsigned short* __restrict__ woT)
{
    int bid = blockIdx.x, t = threadIdx.x;
    if (bid < 192) {
        int n = bid;
        float v;
        if (n < 32)      v = w_theta[t * 32 + n] * 1.44269504f;  // fold log2e -> exp2
        else if (n < 64) v = w_phi[t * 32 + (n - 32)];
        else             v = w_g[t * 128 + (n - 64)];
        WT[n * 256 + t] = f2b(v);
    } else if (t < 128) {
        int cc = bid - 192;
        woT[cc * 128 + t] = f2b(w_o[t * 256 + cc]);
    }
}

// ---------------------------------------------------------------------------
// K1: fused proj + pool (identical to round 14).
// ---------------------------------------------------------------------------
__global__ __launch_bounds__(256) void k_proj(
    const float* __restrict__ x, const unsigned short* __restrict__ WT,
    unsigned short* __restrict__ theta_b, unsigned short* __restrict__ phi_p,
    unsigned short* __restrict__ g_pT)
{
    __shared__ char plds[40960];
    unsigned short* xT = (unsigned short*)plds;            // [128][64k] swz, 16KB
    unsigned short* wT = (unsigned short*)(plds + 16384);  // [192][64k] swz, 24KB

    const int t = threadIdx.x;
    const int w = t >> 6, l = t & 63, G = l >> 4, c = l & 15;
    const int bid = blockIdx.x;
    const int b = bid >> 5, h2 = bid & 31;
    const size_t row0 = (size_t)bid * 128;

    f32x4 acc[2][12];
#pragma unroll
    for (int i = 0; i < 2; i++)
#pragma unroll
        for (int j = 0; j < 12; j++) acc[i][j] = (f32x4){0.f, 0.f, 0.f, 0.f};

    for (int k0 = 0; k0 < 256; k0 += 64) {
        __syncthreads();
#pragma unroll
        for (int it = 0; it < 4; it++) {           // x tile: 128 rows x 8 slots
            int u = it * 256 + t, r = u >> 3, s = u & 7;
            const float* px = x + (row0 + r) * 256 + k0 + s * 8;
            float4 a = *(const float4*)px;
            float4 bq = *(const float4*)(px + 4);
            uint4 v;
            v.x = (unsigned)f2b(a.x) | ((unsigned)f2b(a.y) << 16);
            v.y = (unsigned)f2b(a.z) | ((unsigned)f2b(a.w) << 16);
            v.z = (unsigned)f2b(bq.x) | ((unsigned)f2b(bq.y) << 16);
            v.w = (unsigned)f2b(bq.z) | ((unsigned)f2b(bq.w) << 16);
            *(uint4*)((char*)xT + r * 128 + ((s * 16) ^ ((r & 7) << 4))) = v;
        }
#pragma unroll
        for (int it = 0; it < 6; it++) {           // W tile: 192 rows x 8 slots
            int u = it * 256 + t, r = u >> 3, s = u & 7;
            uint4 v = *(const uint4*)(WT + r * 256 + k0 + s * 8);
            *(uint4*)((char*)wT + r * 128 + ((s * 16) ^ ((r & 7) << 4))) = v;
        }
        __syncthreads();
#pragma unroll
        for (int kin = 0; kin < 2; kin++) {
            int m0r = (2 * w) * 16 + c, m1r = (2 * w + 1) * 16 + c;
            bf16x8 a0 = *(const bf16x8*)((char*)xT + m0r * 128 + ((kin * 64 + G * 16) ^ ((m0r & 7) << 4)));
            bf16x8 a1 = *(const bf16x8*)((char*)xT + m1r * 128 + ((kin * 64 + G * 16) ^ ((m1r & 7) << 4)));
#pragma unroll
            for (int nt = 0; nt < 12; nt++) {
                int nr = nt * 16 + c;
                bf16x8 bv = *(const bf16x8*)((char*)wT + nr * 128 + ((kin * 64 + G * 16) ^ ((nr & 7) << 4)));
                acc[0][nt] = MFMA16(a0, bv, acc[0][nt]);
                acc[1][nt] = MFMA16(a1, bv, acc[1][nt]);
            }
        }
    }

    // theta -> global (full-res), nt 0..1
#pragma unroll
    for (int mt = 0; mt < 2; mt++)
#pragma unroll
        for (int nt = 0; nt < 2; nt++)
#pragma unroll
            for (int i = 0; i < 4; i++) {
                size_t row = row0 + (2 * w + mt) * 16 + 4 * G + i;
                theta_b[row * 32 + nt * 16 + c] = f2b(acc[mt][nt][i]);
            }

    __syncthreads();   // all MFMA reads of xT/wT done before overwrite

    // ww-pooled tile T[64 rows][160 cols]: row = rr*32 + wp, 512B stride
#pragma unroll
    for (int mt = 0; mt < 2; mt++) {
        int rl = 2 * w + mt, rr = rl >> 2, wpb = (rl & 3) * 8 + 2 * G;
#pragma unroll
        for (int nt = 2; nt < 12; nt++) {
            int col = (nt - 2) * 16 + c;
#pragma unroll
            for (int j = 0; j < 2; j++) {
                int row = rr * 32 + wpb + j;
                float m = fmaxf(acc[mt][nt][2 * j], acc[mt][nt][2 * j + 1]);
                *(unsigned short*)(plds + row * 512 + ((2 * col) ^ ((row & 7) << 4))) = f2b(m);
            }
        }
    }
    __syncthreads();

    // phi: rr-pool cols 0..31 -> phi_p[b][h2*32+wp][ch]
    {
        int wp = t >> 3, chb = (t & 7) * 4;
        unsigned short vv[4];
#pragma unroll
        for (int k = 0; k < 4; k++) {
            int colb = 2 * (chb + k);
            unsigned short a = *(const unsigned short*)(plds + wp * 512 + (colb ^ ((wp & 7) << 4)));
            unsigned short e = *(const unsigned short*)(plds + (wp + 32) * 512 + (colb ^ ((wp & 7) << 4)));
            vv[k] = bmax(a, e);
        }
        uint2 pv;
        pv.x = (unsigned)vv[0] | ((unsigned)vv[1] << 16);
        pv.y = (unsigned)vv[2] | ((unsigned)vv[3] << 16);
        *(uint2*)(phi_p + ((size_t)(b * 1024 + h2 * 32 + wp)) * 32 + chb) = pv;
    }
    // g: rr-pool cols 32..159, transpose + k-perm -> g_pT[b][d][h2*32 + s4*8 + k]
#pragma unroll
    for (int it = 0; it < 2; it++) {
        int d = t & 127, s4 = (t >> 7) + 2 * it;
        union { unsigned short v[8]; uint4 q; } pk;
#pragma unroll
        for (int k = 0; k < 8; k++) {
            int wp2 = 16 * (k >> 2) + 4 * s4 + (k & 3);
            int colb = 2 * (32 + d);
            unsigned short a = *(const unsigned short*)(plds + wp2 * 512 + (colb ^ ((wp2 & 7) << 4)));
            unsigned short e = *(const unsigned short*)(plds + (wp2 + 32) * 512 + (colb ^ ((wp2 & 7) << 4)));
            pk.v[k] = bmax(a, e);
        }
        *(uint4*)(g_pT + ((size_t)b * 128 + d) * 1024 + h2 * 32 + s4 * 8) = pk.q;
    }
}

// ---------------------------------------------------------------------------
// K3: fused flash attention (r14 structure, setprio removed). 1024 x 256 thr.
// 4 waves = 2 qg x 2 mg; wave (qg,mg): 32q x 512m as 16 chunks of 32m.
// ONE barrier per chunk: vmcnt(0) -> barrier -> STAGE(next) -> compute.
// ---------------------------------------------------------------------------
__global__ __launch_bounds__(256, 4) void k_attn(
    const unsigned short* __restrict__ theta_b, const unsigned short* __restrict__ phi_p,
    const unsigned short* __restrict__ g_pT, const unsigned short* __restrict__ woT,
    const float* __restrict__ x, const float* __restrict__ b_o,
    const float* __restrict__ sigma_p, float* __restrict__ out)
{
    __shared__ char lds[40960];

    const int t = threadIdx.x;
    const int w = t >> 6, l = t & 63, G = l >> 4, c = l & 15;
    const int qg = w >> 1, mg = w & 1;
    const int bid = (blockIdx.x & 7) * 128 + (blockIdx.x >> 3);   // XCD swizzle (bijective)
    const int b = bid >> 6;
    const int q0 = (bid & 63) * 64;
    const int xr = (c & 7) << 4;

    const unsigned short* gsrc = g_pT + (size_t)b * 131072;
    const unsigned short* psrc = phi_p + (size_t)b * 32768;
    // per wave per chunk: 4 g-loads + 1 phi-load
#define STAGE(BI, MC)                                                               \
    {                                                                               \
        char* gb = lds + mg * 20480 + (BI) * 10240;                                 \
        char* pb = gb + 8192;                                                       \
        const int hp = mg * 16 + (MC);                                              \
        _Pragma("unroll")                                                           \
        for (int it = 0; it < 4; it++) {                                            \
            int d = 64 * qg + 16 * it + (l >> 2);                                   \
            GLOAD16(gsrc + (size_t)d * 1024 + hp * 32 + (l & 3) * 8,                \
                    gb + qg * 4096 + it * 1024 + l * 16);                           \
        }                                                                           \
        {                                                                           \
            int r = 16 * qg + (l >> 2);                                             \
            GLOAD16(psrc + (size_t)(hp * 32 + r) * 32 + (l & 3) * 8,                \
                    pb + qg * 1024 + l * 16);                                       \
        }                                                                           \
    }

    // prologue: stage chunk 0 (both mg) + theta [64q][32ch] plain @10240
    STAGE(0, 0);
    {
        char* th = lds + 10240;
        int r = t >> 2, s = t & 3;
        uint4 v = *(const uint4*)(theta_b + ((size_t)(b * 4096 + q0 + r)) * 32 + s * 8);
        *(uint4*)(th + r * 64 + s * 16) = v;
    }
    __syncthreads();   // chunk0 + theta landed (drains vmcnt+lgkm)

    // wave's theta B-frags (dense reads, no swz)
    const bf16x8 bt0 = *(const bf16x8*)(lds + 10240 + (qg * 32 + c) * 64 + G * 16);
    const bf16x8 bt1 = *(const bf16x8*)(lds + 10240 + (qg * 32 + 16 + c) * 64 + G * 16);
    __syncthreads();   // bt reads done before iter0 stages buf1 (overwrites theta)

    f32x4 oacc[2][8];
#pragma unroll
    for (int qt = 0; qt < 2; qt++)
#pragma unroll
        for (int dt = 0; dt < 8; dt++) oacc[qt][dt] = (f32x4){0.f, 0.f, 0.f, 0.f};
    float ps[2] = {0.f, 0.f};
    const f32x4 zf = (f32x4){0.f, 0.f, 0.f, 0.f};

    for (int mc = 0; mc < 16; mc++) {
        const int cur = mc & 1;
        // my chunk-mc loads landed; barrier => everyone's landed AND everyone
        // finished compute(mc-1) => buf[cur^1] is free to overwrite.
        asm volatile("s_waitcnt vmcnt(0)" ::: "memory");
        __builtin_amdgcn_sched_barrier(0);
        __builtin_amdgcn_s_barrier();
        __builtin_amdgcn_sched_barrier(0);
        if (mc < 15) STAGE(cur ^ 1, mc + 1);    // lands under compute(mc)

        const char* gL   = lds + mg * 20480 + cur * 10240;
        const char* phiL = gL + 8192;

        // S^T = phi @ theta^T (K=32 ch)
        bf16x8 ap0 = *(const bf16x8*)(phiL + c * 64 + G * 16);
        bf16x8 ap1 = *(const bf16x8*)(phiL + (16 + c) * 64 + G * 16);
        f32x4 sacc[2][2];
        sacc[0][0] = MFMA16(ap0, bt0, zf);
        sacc[0][1] = MFMA16(ap1, bt0, zf);
        sacc[1][0] = MFMA16(ap0, bt1, zf);
        sacc[1][1] = MFMA16(ap1, bt1, zf);

        // exp2 (theta pre-scaled by log2e) -> packed P A-frags (cvt_pk) + rowsums
        bf16x8 pa[2];
#pragma unroll
        for (int qt = 0; qt < 2; qt++) {
            union { unsigned u[4]; bf16x8 v; } pu;
#pragma unroll
            for (int mt = 0; mt < 2; mt++)
#pragma unroll
                for (int hf = 0; hf < 2; hf++) {
                    float p0 = fexp2(sacc[qt][mt][2 * hf]);
                    float p1 = fexp2(sacc[qt][mt][2 * hf + 1]);
                    ps[qt] += p0 + p1;
                    pu.u[mt * 2 + hf] = cvt_pk_bf16(p0, p1);
                }
            pa[qt] = pu.v;
        }

        // O += P @ g  (B-frag = one dense b128 per d-tile, feeds both q-tiles)
#pragma unroll
        for (int dt = 0; dt < 8; dt++) {
            bf16x8 bg = *(const bf16x8*)(gL + (dt * 16 + c) * 64 + G * 16);
            oacc[0][dt] = MFMA16(pa[0], bg, oacc[0][dt]);
            oacc[1][dt] = MFMA16(pa[1], bg, oacc[1][dt]);
        }
    }
#undef STAGE
    __syncthreads();   // all compute(15) reads done before combine overwrites lds

    // wave-level rowsum reduce: lanes {c,c+16,c+32,c+48} -> total for q-col c
#pragma unroll
    for (int qt = 0; qt < 2; qt++) {
        ps[qt] += __shfl_xor(ps[qt], 16);
        ps[qt] += __shfl_xor(ps[qt], 32);
    }

    // ---- combine m-group partials ----
    if (mg == 1) {
        char* po = lds + qg * 16640;
#pragma unroll
        for (int qt = 0; qt < 2; qt++)
#pragma unroll
            for (int dt = 0; dt < 8; dt++)
#pragma unroll
                for (int i = 0; i < 4; i++)
                    *(float*)(po + (qt * 16 + 4 * G + i) * 520 + (dt * 16 + c) * 4) =
                        oacc[qt][dt][i];
        if (l < 16) {
            *(float*)(lds + 33280 + (qg * 32 + l) * 4)      = ps[0];
            *(float*)(lds + 33280 + (qg * 32 + 16 + l) * 4) = ps[1];
        }
    }
    __syncthreads();
    if (mg == 0) {
        const char* po = lds + qg * 16640;
#pragma unroll
        for (int qt = 0; qt < 2; qt++)
#pragma unroll
            for (int dt = 0; dt < 8; dt++) {
                f32x4 a = oacc[qt][dt];
#pragma unroll
                for (int i = 0; i < 4; i++)
                    a[i] += *(const float*)(po + (qt * 16 + 4 * G + i) * 520 + (dt * 16 + c) * 4);
                oacc[qt][dt] = a;
            }
#pragma unroll
        for (int qt = 0; qt < 2; qt++)
            ps[qt] += *(const float*)(lds + 33280 + (qg * 32 + qt * 16 + c) * 4);
        float rinv[2][4];
#pragma unroll
        for (int qt = 0; qt < 2; qt++)
#pragma unroll
            for (int i = 0; i < 4; i++)
                rinv[qt][i] = 1.0f / __shfl(ps[qt], 4 * G + i);
        // write normalized bf16 O rows
        char* Or = lds + qg * 16640;
#pragma unroll
        for (int qt = 0; qt < 2; qt++)
#pragma unroll
            for (int dt = 0; dt < 8; dt++)
#pragma unroll
                for (int i = 0; i < 4; i++) {
                    int r32 = qt * 16 + 4 * G + i, d = dt * 16 + c;
                    *(unsigned short*)(Or + r32 * 256 + ((d * 2) ^ ((r32 & 7) << 4))) =
                        f2b(oacc[qt][dt][i] * rinv[qt][i]);
                }
    }
    __syncthreads();   // O visible to all

    // ---- epilogue: out = x + sigma * (O @ w_o + b_o). Wave w: rows w*16..+16 ----
    const float sg = *sigma_p;
    const char* O_r = lds + (w >> 1) * 16640 + ((w & 1) * 16 + c) * 256;  // row w*16+c
    char* wo_l = lds + 8448;
    bf16x8 aO[4];
#pragma unroll
    for (int ks = 0; ks < 4; ks++)
        aO[ks] = *(const bf16x8*)(O_r + ((ks * 64 + G * 16) ^ xr));

    for (int cb = 0; cb < 8; cb++) {
        __syncthreads();                         // prev wo_l reads done
#pragma unroll
        for (int it = 0; it < 2; it++) {         // stage woT slice [32 c][128 d] = 8KB
            int u = it * 256 + t, r = u >> 4, s = u & 15;
            uint4 v = *(const uint4*)(woT + (size_t)(cb * 32 + r) * 128 + s * 8);
            *(uint4*)(wo_l + r * 256 + ((s * 16) ^ ((r & 7) << 4))) = v;
        }
        __syncthreads();
        f32x4 eacc[2];
#pragma unroll
        for (int ct = 0; ct < 2; ct++) eacc[ct] = (f32x4){0.f, 0.f, 0.f, 0.f};
#pragma unroll
        for (int ks = 0; ks < 4; ks++) {
#pragma unroll
            for (int ct = 0; ct < 2; ct++) {
                bf16x8 bw = *(const bf16x8*)(wo_l + (ct * 16 + c) * 256 + ((ks * 64 + G * 16) ^ xr));
                eacc[ct] = MFMA16(aO[ks], bw, eacc[ct]);
            }
        }
#pragma unroll
        for (int ct = 0; ct < 2; ct++) {
            int col = cb * 32 + ct * 16 + c;
            float bo = b_o[col];
#pragma unroll
            for (int i = 0; i < 4; i++) {
                size_t off = ((size_t)(b * 4096 + q0 + w * 16 + 4 * G + i)) * 256 + col;
                out[off] = x[off] + sg * (eacc[ct][i] + bo);
            }
        }
    }
}

// ---------------------------------------------------------------------------
extern "C" void kernel_launch(void* const* d_in, const int* in_sizes, int n_in,
                              void* d_out, int out_size, void* d_ws, size_t ws_size,
                              hipStream_t stream)
{
    const float* x       = (const float*)d_in[0];
    const float* w_theta = (const float*)d_in[1];
    const float* w_phi   = (const float*)d_in[2];
    const float* w_g     = (const float*)d_in[3];
    const float* w_o     = (const float*)d_in[4];
    const float* b_o     = (const float*)d_in[5];
    const float* sigma   = (const float*)d_in[6];
    float* out = (float*)d_out;

    char* ws = (char*)d_ws;
    unsigned short* theta_b = (unsigned short*)(ws);              //  4 MB [B,4096,32]
    unsigned short* phi_p   = (unsigned short*)(ws + 4194304);    //  1 MB [B,1024,32]
    unsigned short* g_pT    = (unsigned short*)(ws + 5242880);    //  4 MB [B,128,1024] k-perm
    unsigned short* WT      = (unsigned short*)(ws + 9437184);    // 96 KB [192,256]
    unsigned short* woT     = (unsigned short*)(ws + 9535488);    // 64 KB [256,128]

    hipLaunchKernelGGL(k_prep, dim3(448), dim3(256), 0, stream,
                       w_theta, w_phi, w_g, w_o, WT, woT);
    hipLaunchKernelGGL(k_proj, dim3(512), dim3(256), 0, stream,
                       x, WT, theta_b, phi_p, g_pT);
    hipLaunchKernelGGL(k_attn, dim3(1024), dim3(256), 0, stream,
                       theta_b, phi_p, g_pT, woT, x, b_o, sigma, out);
}

// Round 20
// 68.825 us; speedup vs baseline: 2.2977x; 1.0130x over previous
//
#include <hip/hip_runtime.h>
#include <hip/hip_bf16.h>

// SNNonLocalBlock: B=16, H=W=64, C=256, L=4096, Ld=1024
// FINAL (= Round 14, best verified: 68.9us total, k_attn 52.3us, absmax 0.031).
// k_prep: weight transpose + exp2 fold. k_proj: fused projection GEMM + 2x2
// maxpool (in-register ww-pool + LDS rr-pool), emits theta/phi_p/g_pT (k-perm).
// k_attn: MFMA flash attention, 4 waves = 2qg x 2mg, 16 chunks of 32m,
// global_load_lds double-buffer, 1 barrier/chunk, cvt_pk P-packing,
// in-LDS m-group combine, fused w_o + bias + residual epilogue.

typedef __attribute__((ext_vector_type(8))) short bf16x8;
typedef __attribute__((ext_vector_type(4))) float f32x4;

#define MFMA16(A,B,C) __builtin_amdgcn_mfma_f32_16x16x32_bf16(A,B,C,0,0,0)

#define GLOAD16(GSRC, LDST)                                                        \
    __builtin_amdgcn_global_load_lds(                                              \
        (const __attribute__((address_space(1))) unsigned int*)(GSRC),             \
        (__attribute__((address_space(3))) unsigned int*)(LDST), 16, 0, 0)

static __device__ __forceinline__ unsigned short f2b(float f) {
    __hip_bfloat16 h = __float2bfloat16(f);
    return *reinterpret_cast<unsigned short*>(&h);
}
static __device__ __forceinline__ unsigned short bmax(unsigned short a, unsigned short b) {
    return (__uint_as_float((unsigned)a << 16) > __uint_as_float((unsigned)b << 16)) ? a : b;
}
static __device__ __forceinline__ float fexp2(float f) {
    return __builtin_amdgcn_exp2f(f);
}
static __device__ __forceinline__ unsigned cvt_pk_bf16(float lo, float hi) {
    unsigned r;
    asm("v_cvt_pk_bf16_f32 %0, %1, %2" : "=v"(r) : "v"(lo), "v"(hi));
    return r;
}

// ---------------------------------------------------------------------------
// K0: prep: WT[192 n][256 k] bf16 = [w_theta*log2e | w_phi | w_g]^T ;
//           woT[256 c][128 d] bf16
// ---------------------------------------------------------------------------
__global__ void k_prep(const float* __restrict__ w_theta, const float* __restrict__ w_phi,
                       const float* __restrict__ w_g, const float* __restrict__ w_o,
                       unsigned short* __restrict__ WT, unsigned short* __restrict__ woT)
{
    int bid = blockIdx.x, t = threadIdx.x;
    if (bid < 192) {
        int n = bid;
        float v;
        if (n < 32)      v = w_theta[t * 32 + n] * 1.44269504f;  // fold log2e -> exp2
        else if (n < 64) v = w_phi[t * 32 + (n - 32)];
        else             v = w_g[t * 128 + (n - 64)];
        WT[n * 256 + t] = f2b(v);
    } else if (t < 128) {
        int cc = bid - 192;
        woT[cc * 128 + t] = f2b(w_o[t * 256 + cc]);
    }
}

// ---------------------------------------------------------------------------
// K1: fused proj + pool. 512 blocks x 128 rows; block bid = b*32 + h2 covers
// image rows {2h2, 2h2+1} x 64 cols. theta -> global full-res; phi/g pooled.
// ---------------------------------------------------------------------------
__global__ __launch_bounds__(256) void k_proj(
    const float* __restrict__ x, const unsigned short* __restrict__ WT,
    unsigned short* __restrict__ theta_b, unsigned short* __restrict__ phi_p,
    unsigned short* __restrict__ g_pT)
{
    __shared__ char plds[40960];
    unsigned short* xT = (unsigned short*)plds;            // [128][64k] swz, 16KB
    unsigned short* wT = (unsigned short*)(plds + 16384);  // [192][64k] swz, 24KB

    const int t = threadIdx.x;
    const int w = t >> 6, l = t & 63, G = l >> 4, c = l & 15;
    const int bid = blockIdx.x;
    const int b = bid >> 5, h2 = bid & 31;
    const size_t row0 = (size_t)bid * 128;

    f32x4 acc[2][12];
#pragma unroll
    for (int i = 0; i < 2; i++)
#pragma unroll
        for (int j = 0; j < 12; j++) acc[i][j] = (f32x4){0.f, 0.f, 0.f, 0.f};

    for (int k0 = 0; k0 < 256; k0 += 64) {
        __syncthreads();
#pragma unroll
        for (int it = 0; it < 4; it++) {           // x tile: 128 rows x 8 slots
            int u = it * 256 + t, r = u >> 3, s = u & 7;
            const float* px = x + (row0 + r) * 256 + k0 + s * 8;
            float4 a = *(const float4*)px;
            float4 bq = *(const float4*)(px + 4);
            uint4 v;
            v.x = (unsigned)f2b(a.x) | ((unsigned)f2b(a.y) << 16);
            v.y = (unsigned)f2b(a.z) | ((unsigned)f2b(a.w) << 16);
            v.z = (unsigned)f2b(bq.x) | ((unsigned)f2b(bq.y) << 16);
            v.w = (unsigned)f2b(bq.z) | ((unsigned)f2b(bq.w) << 16);
            *(uint4*)((char*)xT + r * 128 + ((s * 16) ^ ((r & 7) << 4))) = v;
        }
#pragma unroll
        for (int it = 0; it < 6; it++) {           // W tile: 192 rows x 8 slots
            int u = it * 256 + t, r = u >> 3, s = u & 7;
            uint4 v = *(const uint4*)(WT + r * 256 + k0 + s * 8);
            *(uint4*)((char*)wT + r * 128 + ((s * 16) ^ ((r & 7) << 4))) = v;
        }
        __syncthreads();
#pragma unroll
        for (int kin = 0; kin < 2; kin++) {
            int m0r = (2 * w) * 16 + c, m1r = (2 * w + 1) * 16 + c;
            bf16x8 a0 = *(const bf16x8*)((char*)xT + m0r * 128 + ((kin * 64 + G * 16) ^ ((m0r & 7) << 4)));
            bf16x8 a1 = *(const bf16x8*)((char*)xT + m1r * 128 + ((kin * 64 + G * 16) ^ ((m1r & 7) << 4)));
#pragma unroll
            for (int nt = 0; nt < 12; nt++) {
                int nr = nt * 16 + c;
                bf16x8 bv = *(const bf16x8*)((char*)wT + nr * 128 + ((kin * 64 + G * 16) ^ ((nr & 7) << 4)));
                acc[0][nt] = MFMA16(a0, bv, acc[0][nt]);
                acc[1][nt] = MFMA16(a1, bv, acc[1][nt]);
            }
        }
    }

    // theta -> global (full-res), nt 0..1
#pragma unroll
    for (int mt = 0; mt < 2; mt++)
#pragma unroll
        for (int nt = 0; nt < 2; nt++)
#pragma unroll
            for (int i = 0; i < 4; i++) {
                size_t row = row0 + (2 * w + mt) * 16 + 4 * G + i;
                theta_b[row * 32 + nt * 16 + c] = f2b(acc[mt][nt][i]);
            }

    __syncthreads();   // all MFMA reads of xT/wT done before overwrite

    // ww-pooled tile T[64 rows][160 cols]: row = rr*32 + wp, 512B stride
#pragma unroll
    for (int mt = 0; mt < 2; mt++) {
        int rl = 2 * w + mt, rr = rl >> 2, wpb = (rl & 3) * 8 + 2 * G;
#pragma unroll
        for (int nt = 2; nt < 12; nt++) {
            int col = (nt - 2) * 16 + c;
#pragma unroll
            for (int j = 0; j < 2; j++) {
                int row = rr * 32 + wpb + j;
                float m = fmaxf(acc[mt][nt][2 * j], acc[mt][nt][2 * j + 1]);
                *(unsigned short*)(plds + row * 512 + ((2 * col) ^ ((row & 7) << 4))) = f2b(m);
            }
        }
    }
    __syncthreads();

    // phi: rr-pool cols 0..31 -> phi_p[b][h2*32+wp][ch]
    {
        int wp = t >> 3, chb = (t & 7) * 4;
        unsigned short vv[4];
#pragma unroll
        for (int k = 0; k < 4; k++) {
            int colb = 2 * (chb + k);
            unsigned short a = *(const unsigned short*)(plds + wp * 512 + (colb ^ ((wp & 7) << 4)));
            unsigned short e = *(const unsigned short*)(plds + (wp + 32) * 512 + (colb ^ ((wp & 7) << 4)));
            vv[k] = bmax(a, e);
        }
        uint2 pv;
        pv.x = (unsigned)vv[0] | ((unsigned)vv[1] << 16);
        pv.y = (unsigned)vv[2] | ((unsigned)vv[3] << 16);
        *(uint2*)(phi_p + ((size_t)(b * 1024 + h2 * 32 + wp)) * 32 + chb) = pv;
    }
    // g: rr-pool cols 32..159, transpose + k-perm -> g_pT[b][d][h2*32 + s4*8 + k]
#pragma unroll
    for (int it = 0; it < 2; it++) {
        int d = t & 127, s4 = (t >> 7) + 2 * it;
        union { unsigned short v[8]; uint4 q; } pk;
#pragma unroll
        for (int k = 0; k < 8; k++) {
            int wp2 = 16 * (k >> 2) + 4 * s4 + (k & 3);
            int colb = 2 * (32 + d);
            unsigned short a = *(const unsigned short*)(plds + wp2 * 512 + (colb ^ ((wp2 & 7) << 4)));
            unsigned short e = *(const unsigned short*)(plds + (wp2 + 32) * 512 + (colb ^ ((wp2 & 7) << 4)));
            pk.v[k] = bmax(a, e);
        }
        *(uint4*)(g_pT + ((size_t)b * 128 + d) * 1024 + h2 * 32 + s4 * 8) = pk.q;
    }
}

// ---------------------------------------------------------------------------
// K3: fused flash attention. 1024 blocks x 256 thr.
// 4 waves = 2 qg x 2 mg; wave (qg,mg): 32q x 512m as 16 chunks of 32m.
// ONE barrier per chunk: vmcnt(0) -> barrier -> STAGE(next) -> compute.
// ---------------------------------------------------------------------------
__global__ __launch_bounds__(256, 4) void k_attn(
    const unsigned short* __restrict__ theta_b, const unsigned short* __restrict__ phi_p,
    const unsigned short* __restrict__ g_pT, const unsigned short* __restrict__ woT,
    const float* __restrict__ x, const float* __restrict__ b_o,
    const float* __restrict__ sigma_p, float* __restrict__ out)
{
    __shared__ char lds[40960];

    const int t = threadIdx.x;
    const int w = t >> 6, l = t & 63, G = l >> 4, c = l & 15;
    const int qg = w >> 1, mg = w & 1;
    const int bid = (blockIdx.x & 7) * 128 + (blockIdx.x >> 3);   // XCD swizzle (bijective)
    const int b = bid >> 6;
    const int q0 = (bid & 63) * 64;
    const int xr = (c & 7) << 4;

    const unsigned short* gsrc = g_pT + (size_t)b * 131072;
    const unsigned short* psrc = phi_p + (size_t)b * 32768;
    // per wave per chunk: 4 g-loads + 1 phi-load
#define STAGE(BI, MC)                                                               \
    {                                                                               \
        char* gb = lds + mg * 20480 + (BI) * 10240;                                 \
        char* pb = gb + 8192;                                                       \
        const int hp = mg * 16 + (MC);                                              \
        _Pragma("unroll")                                                           \
        for (int it = 0; it < 4; it++) {                                            \
            int d = 64 * qg + 16 * it + (l >> 2);                                   \
            GLOAD16(gsrc + (size_t)d * 1024 + hp * 32 + (l & 3) * 8,                \
                    gb + qg * 4096 + it * 1024 + l * 16);                           \
        }                                                                           \
        {                                                                           \
            int r = 16 * qg + (l >> 2);                                             \
            GLOAD16(psrc + (size_t)(hp * 32 + r) * 32 + (l & 3) * 8,                \
                    pb + qg * 1024 + l * 16);                                       \
        }                                                                           \
    }

    // prologue: stage chunk 0 (both mg) + theta [64q][32ch] plain @10240
    STAGE(0, 0);
    {
        char* th = lds + 10240;
        int r = t >> 2, s = t & 3;
        uint4 v = *(const uint4*)(theta_b + ((size_t)(b * 4096 + q0 + r)) * 32 + s * 8);
        *(uint4*)(th + r * 64 + s * 16) = v;
    }
    __syncthreads();   // chunk0 + theta landed (drains vmcnt+lgkm)

    // wave's theta B-frags (dense reads, no swz)
    const bf16x8 bt0 = *(const bf16x8*)(lds + 10240 + (qg * 32 + c) * 64 + G * 16);
    const bf16x8 bt1 = *(const bf16x8*)(lds + 10240 + (qg * 32 + 16 + c) * 64 + G * 16);
    __syncthreads();   // bt reads done before iter0 stages buf1 (overwrites theta)

    f32x4 oacc[2][8];
#pragma unroll
    for (int qt = 0; qt < 2; qt++)
#pragma unroll
        for (int dt = 0; dt < 8; dt++) oacc[qt][dt] = (f32x4){0.f, 0.f, 0.f, 0.f};
    float ps[2] = {0.f, 0.f};
    const f32x4 zf = (f32x4){0.f, 0.f, 0.f, 0.f};

    for (int mc = 0; mc < 16; mc++) {
        const int cur = mc & 1;
        // my chunk-mc loads landed; barrier => everyone's landed AND everyone
        // finished compute(mc-1) => buf[cur^1] is free to overwrite.
        asm volatile("s_waitcnt vmcnt(0)" ::: "memory");
        __builtin_amdgcn_sched_barrier(0);
        __builtin_amdgcn_s_barrier();
        __builtin_amdgcn_sched_barrier(0);
        if (mc < 15) STAGE(cur ^ 1, mc + 1);    // lands under compute(mc)

        const char* gL   = lds + mg * 20480 + cur * 10240;
        const char* phiL = gL + 8192;

        // S^T = phi @ theta^T (K=32 ch)
        bf16x8 ap0 = *(const bf16x8*)(phiL + c * 64 + G * 16);
        bf16x8 ap1 = *(const bf16x8*)(phiL + (16 + c) * 64 + G * 16);
        f32x4 sacc[2][2];
        __builtin_amdgcn_s_setprio(1);
        sacc[0][0] = MFMA16(ap0, bt0, zf);
        sacc[0][1] = MFMA16(ap1, bt0, zf);
        sacc[1][0] = MFMA16(ap0, bt1, zf);
        sacc[1][1] = MFMA16(ap1, bt1, zf);
        __builtin_amdgcn_s_setprio(0);

        // exp2 (theta pre-scaled by log2e) -> packed P A-frags (cvt_pk) + rowsums
        bf16x8 pa[2];
#pragma unroll
        for (int qt = 0; qt < 2; qt++) {
            union { unsigned u[4]; bf16x8 v; } pu;
#pragma unroll
            for (int mt = 0; mt < 2; mt++)
#pragma unroll
                for (int hf = 0; hf < 2; hf++) {
                    float p0 = fexp2(sacc[qt][mt][2 * hf]);
                    float p1 = fexp2(sacc[qt][mt][2 * hf + 1]);
                    ps[qt] += p0 + p1;
                    pu.u[mt * 2 + hf] = cvt_pk_bf16(p0, p1);
                }
            pa[qt] = pu.v;
        }

        // O += P @ g  (B-frag = one dense b128 per d-tile, feeds both q-tiles)
        __builtin_amdgcn_s_setprio(1);
#pragma unroll
        for (int dt = 0; dt < 8; dt++) {
            bf16x8 bg = *(const bf16x8*)(gL + (dt * 16 + c) * 64 + G * 16);
            oacc[0][dt] = MFMA16(pa[0], bg, oacc[0][dt]);
            oacc[1][dt] = MFMA16(pa[1], bg, oacc[1][dt]);
        }
        __builtin_amdgcn_s_setprio(0);
    }
#undef STAGE
    __syncthreads();   // all compute(15) reads done before combine overwrites lds

    // wave-level rowsum reduce: lanes {c,c+16,c+32,c+48} -> total for q-col c
#pragma unroll
    for (int qt = 0; qt < 2; qt++) {
        ps[qt] += __shfl_xor(ps[qt], 16);
        ps[qt] += __shfl_xor(ps[qt], 32);
    }

    // ---- combine m-group partials ----
    if (mg == 1) {
        char* po = lds + qg * 16640;
#pragma unroll
        for (int qt = 0; qt < 2; qt++)
#pragma unroll
            for (int dt = 0; dt < 8; dt++)
#pragma unroll
                for (int i = 0; i < 4; i++)
                    *(float*)(po + (qt * 16 + 4 * G + i) * 520 + (dt * 16 + c) * 4) =
                        oacc[qt][dt][i];
        if (l < 16) {
            *(float*)(lds + 33280 + (qg * 32 + l) * 4)      = ps[0];
            *(float*)(lds + 33280 + (qg * 32 + 16 + l) * 4) = ps[1];
        }
    }
    __syncthreads();
    if (mg == 0) {
        const char* po = lds + qg * 16640;
#pragma unroll
        for (int qt = 0; qt < 2; qt++)
#pragma unroll
            for (int dt = 0; dt < 8; dt++) {
                f32x4 a = oacc[qt][dt];
#pragma unroll
                for (int i = 0; i < 4; i++)
                    a[i] += *(const float*)(po + (qt * 16 + 4 * G + i) * 520 + (dt * 16 + c) * 4);
                oacc[qt][dt] = a;
            }
#pragma unroll
        for (int qt = 0; qt < 2; qt++)
            ps[qt] += *(const float*)(lds + 33280 + (qg * 32 + qt * 16 + c) * 4);
        float rinv[2][4];
#pragma unroll
        for (int qt = 0; qt < 2; qt++)
#pragma unroll
            for (int i = 0; i < 4; i++)
                rinv[qt][i] = 1.0f / __shfl(ps[qt], 4 * G + i);
        // write normalized bf16 O rows
        char* Or = lds + qg * 16640;
#pragma unroll
        for (int qt = 0; qt < 2; qt++)
#pragma unroll
            for (int dt = 0; dt < 8; dt++)
#pragma unroll
                for (int i = 0; i < 4; i++) {
                    int r32 = qt * 16 + 4 * G + i, d = dt * 16 + c;
                    *(unsigned short*)(Or + r32 * 256 + ((d * 2) ^ ((r32 & 7) << 4))) =
                        f2b(oacc[qt][dt][i] * rinv[qt][i]);
                }
    }
    __syncthreads();   // O visible to all

    // ---- epilogue: out = x + sigma * (O @ w_o + b_o). Wave w: rows w*16..+16 ----
    const float sg = *sigma_p;
    const char* O_r = lds + (w >> 1) * 16640 + ((w & 1) * 16 + c) * 256;  // row w*16+c
    char* wo_l = lds + 8448;
    bf16x8 aO[4];
#pragma unroll
    for (int ks = 0; ks < 4; ks++)
        aO[ks] = *(const bf16x8*)(O_r + ((ks * 64 + G * 16) ^ xr));

    for (int cb = 0; cb < 8; cb++) {
        __syncthreads();                         // prev wo_l reads done
#pragma unroll
        for (int it = 0; it < 2; it++) {         // stage woT slice [32 c][128 d] = 8KB
            int u = it * 256 + t, r = u >> 4, s = u & 15;
            uint4 v = *(const uint4*)(woT + (size_t)(cb * 32 + r) * 128 + s * 8);
            *(uint4*)(wo_l + r * 256 + ((s * 16) ^ ((r & 7) << 4))) = v;
        }
        __syncthreads();
        f32x4 eacc[2];
#pragma unroll
        for (int ct = 0; ct < 2; ct++) eacc[ct] = (f32x4){0.f, 0.f, 0.f, 0.f};
#pragma unroll
        for (int ks = 0; ks < 4; ks++) {
#pragma unroll
            for (int ct = 0; ct < 2; ct++) {
                bf16x8 bw = *(const bf16x8*)(wo_l + (ct * 16 + c) * 256 + ((ks * 64 + G * 16) ^ xr));
                eacc[ct] = MFMA16(aO[ks], bw, eacc[ct]);
            }
        }
#pragma unroll
        for (int ct = 0; ct < 2; ct++) {
            int col = cb * 32 + ct * 16 + c;
            float bo = b_o[col];
#pragma unroll
            for (int i = 0; i < 4; i++) {
                size_t off = ((size_t)(b * 4096 + q0 + w * 16 + 4 * G + i)) * 256 + col;
                out[off] = x[off] + sg * (eacc[ct][i] + bo);
            }
        }
    }
}

// ---------------------------------------------------------------------------
extern "C" void kernel_launch(void* const* d_in, const int* in_sizes, int n_in,
                              void* d_out, int out_size, void* d_ws, size_t ws_size,
                              hipStream_t stream)
{
    const float* x       = (const float*)d_in[0];
    const float* w_theta = (const float*)d_in[1];
    const float* w_phi   = (const float*)d_in[2];
    const float* w_g     = (const float*)d_in[3];
    const float* w_o     = (const float*)d_in[4];
    const float* b_o     = (const float*)d_in[5];
    const float* sigma   = (const float*)d_in[6];
    float* out = (float*)d_out;

    char* ws = (char*)d_ws;
    unsigned short* theta_b = (unsigned short*)(ws);              //  4 MB [B,4096,32]
    unsigned short* phi_p   = (unsigned short*)(ws + 4194304);    //  1 MB [B,1024,32]
    unsigned short* g_pT    = (unsigned short*)(ws + 5242880);    //  4 MB [B,128,1024] k-perm
    unsigned short* WT      = (unsigned short*)(ws + 9437184);    // 96 KB [192,256]
    unsigned short* woT     = (unsigned short*)(ws + 9535488);    // 64 KB [256,128]

    hipLaunchKernelGGL(k_prep, dim3(448), dim3(256), 0, stream,
                       w_theta, w_phi, w_g, w_o, WT, woT);
    hipLaunchKernelGGL(k_proj, dim3(512), dim3(256), 0, stream,
                       x, WT, theta_b, phi_p, g_pT);
    hipLaunchKernelGGL(k_attn, dim3(1024), dim3(256), 0, stream,
                       theta_b, phi_p, g_pT, woT, x, b_o, sigma, out);
}